// Round 4
// baseline (611.034 us; speedup 1.0000x reference)
//
#include <hip/hip_runtime.h>
#include <cstdint>
#include <cstddef>

// Problem constants
#define T_TOKENS 4096   // B*S
#define DDIM     1024
#define HDIM     4096
#define NEXP     8
#define MAXROWS  9216   // 8192 slots + 8*128 padding worst case
#define MAXTILES 72     // MAXROWS/128

typedef __attribute__((ext_vector_type(8))) short bf16x8;
typedef __attribute__((ext_vector_type(4))) float f32x4;

__device__ __forceinline__ unsigned short f2bf(float x) {
  union { float f; unsigned int u; } v; v.f = x;
  unsigned int r = v.u + 0x7fffu + ((v.u >> 16) & 1u);   // RNE
  return (unsigned short)(r >> 16);
}
__device__ __forceinline__ float bf2f(unsigned short b) {
  union { unsigned int u; float f; } v; v.u = ((unsigned int)b) << 16;
  return v.f;
}
__device__ __forceinline__ void async_cp16(const void* g, void* l) {
  __builtin_amdgcn_global_load_lds(
      (__attribute__((address_space(1))) void*)g,
      (__attribute__((address_space(3))) void*)l, 16, 0, 0);
}
__device__ __forceinline__ int swz(int r) { return (r ^ (r >> 3)) & 7; }

// ---------------- router: logits, softmax, top-2, stats ----------------
__global__ __launch_bounds__(256)
void moe_router(const float* __restrict__ x, const float* __restrict__ rw,
                int* __restrict__ tk_idx, float* __restrict__ tk_prob,
                int* __restrict__ counts, float* __restrict__ meanprob) {
  __shared__ float sp[NEXP];
  __shared__ int   sc[NEXP];
  const int tid = threadIdx.x;
  if (tid < NEXP) { sp[tid] = 0.f; sc[tid] = 0; }
  __syncthreads();
  const int wave = tid >> 6, lane = tid & 63;
  const int t = blockIdx.x * 4 + wave;
  float acc[NEXP] = {};
  for (int i = 0; i < 16; ++i) {
    const int d = i * 64 + lane;
    const float xv = x[(size_t)t * DDIM + d];
#pragma unroll
    for (int e = 0; e < NEXP; ++e) acc[e] += xv * rw[e * DDIM + d];
  }
#pragma unroll
  for (int e = 0; e < NEXP; ++e) {
#pragma unroll
    for (int m = 32; m >= 1; m >>= 1) acc[e] += __shfl_xor(acc[e], m);
  }
  if (lane == 0) {
    float mx = acc[0];
#pragma unroll
    for (int e = 1; e < NEXP; ++e) mx = fmaxf(mx, acc[e]);
    float p[NEXP], s = 0.f;
#pragma unroll
    for (int e = 0; e < NEXP; ++e) { p[e] = expf(acc[e] - mx); s += p[e]; }
    const float inv = 1.f / s;
#pragma unroll
    for (int e = 0; e < NEXP; ++e) p[e] *= inv;
    int i0 = 0;
#pragma unroll
    for (int e = 1; e < NEXP; ++e) if (p[e] > p[i0]) i0 = e;
    int i1 = (i0 == 0) ? 1 : 0;
#pragma unroll
    for (int e = 0; e < NEXP; ++e) if (e != i0 && p[e] > p[i1]) i1 = e;
    const float dn = 1.f / (p[i0] + p[i1] + 1e-8f);
    tk_idx[2 * t] = i0; tk_idx[2 * t + 1] = i1;
    tk_prob[2 * t] = p[i0] * dn; tk_prob[2 * t + 1] = p[i1] * dn;
#pragma unroll
    for (int e = 0; e < NEXP; ++e) atomicAdd(&sp[e], p[e]);
    atomicAdd(&sc[i0], 1); atomicAdd(&sc[i1], 1);
  }
  __syncthreads();
  if (tid < NEXP) {
    atomicAdd(&counts[tid], sc[tid]);
    atomicAdd(&meanprob[tid], sp[tid]);
  }
}

// ------- assign: offsets + loss + deterministic slot assignment (no atomics) -------
__global__ __launch_bounds__(256)
void moe_assign(const int* __restrict__ counts, const int* __restrict__ tk_idx,
                int* __restrict__ slot_of, int* __restrict__ off_out,
                const float* __restrict__ meanprob, float* __restrict__ loss_out) {
  const int e = blockIdx.x;
  const int tid = threadIdx.x;
  int off[NEXP + 1];
  off[0] = 0;
#pragma unroll
  for (int i = 0; i < NEXP; ++i) off[i + 1] = off[i] + ((counts[i] + 127) & ~127);
  if (e == 0 && tid == 0) {
#pragma unroll
    for (int i = 0; i <= NEXP; ++i) off_out[i] = off[i];
    float loss = 0.f;
#pragma unroll
    for (int i = 0; i < NEXP; ++i) loss += meanprob[i] * (float)counts[i];
    loss_out[0] = loss * (8.f / (4096.f * 8192.f));
  }
  __shared__ int wsum[4];
  int cursor = off[e];
  const int lane = tid & 63, w = tid >> 6;
  for (int i0 = 0; i0 < T_TOKENS * 2; i0 += 256) {
    const int idx = i0 + tid;
    const int match = (tk_idx[idx] == e) ? 1 : 0;
    const unsigned long long b = __ballot(match);
    if (lane == 0) wsum[w] = __popcll(b);
    __syncthreads();
    int wbase = cursor;
    for (int j = 0; j < 4; ++j) { if (j == w) break; wbase += wsum[j]; }
    if (match) slot_of[idx] = wbase + __popcll(b & ((1ull << lane) - 1ull));
    cursor += wsum[0] + wsum[1] + wsum[2] + wsum[3];
    __syncthreads();
  }
}

// ---------------- scatter: gather x rows -> bf16 slots ----------------
__global__ __launch_bounds__(256)
void moe_scatter(const float* __restrict__ x, const int* __restrict__ slot_of,
                 unsigned short* __restrict__ Xg) {
  const int wave = threadIdx.x >> 6, lane = threadIdx.x & 63;
  const int t = blockIdx.x * 4 + wave;
  const int pos0 = slot_of[2 * t], pos1 = slot_of[2 * t + 1];
#pragma unroll
  for (int i = 0; i < 4; ++i) {
    const int d4 = (i * 64 + lane) * 4;
    const float4 f = *(const float4*)(x + (size_t)t * DDIM + d4);
    ushort4 u;
    u.x = f2bf(f.x); u.y = f2bf(f.y); u.z = f2bf(f.z); u.w = f2bf(f.w);
    *(ushort4*)(Xg + (size_t)pos0 * DDIM + d4) = u;
    *(ushort4*)(Xg + (size_t)pos1 * DDIM + d4) = u;
  }
}

// ------- convert+transpose: fp32 [E][K][N] -> bf16 [E][N][K] -------
// 64x64 tile. Per-thread 4x4 register micro-transpose -> vector ds_write_b64
// into LDS [n][k] (stride 72) -> TWO ds_read_b128 per thread -> 2x16B stores.
// (Round-3 bug: single uint4 per thread covered only half the k-range.)
__global__ __launch_bounds__(256)
void moe_convw(const float* __restrict__ src, unsigned short* __restrict__ dst,
               int K, int N) {
  __shared__ unsigned short LT[64 * 72];   // [n][k], stride 72 shorts
  const int n0 = blockIdx.x * 64, k0 = blockIdx.y * 64, e = blockIdx.z;
  const int tid = threadIdx.x;
  const int c4 = (tid & 15) * 4;     // n offset within tile
  const int r4 = (tid >> 4) * 4;     // k offset within tile
  const float* s = src + ((size_t)e * K + k0 + r4) * N + n0 + c4;
  float4 f[4];
#pragma unroll
  for (int i = 0; i < 4; ++i) f[i] = *(const float4*)(s + (size_t)i * N);
#pragma unroll
  for (int j = 0; j < 4; ++j) {
    ushort4 u;
    const float a0 = (j == 0) ? f[0].x : (j == 1) ? f[0].y : (j == 2) ? f[0].z : f[0].w;
    const float a1 = (j == 0) ? f[1].x : (j == 1) ? f[1].y : (j == 2) ? f[1].z : f[1].w;
    const float a2 = (j == 0) ? f[2].x : (j == 1) ? f[2].y : (j == 2) ? f[2].z : f[2].w;
    const float a3 = (j == 0) ? f[3].x : (j == 1) ? f[3].y : (j == 2) ? f[3].z : f[3].w;
    u.x = f2bf(a0); u.y = f2bf(a1); u.z = f2bf(a2); u.w = f2bf(a3);
    *(ushort4*)&LT[(c4 + j) * 72 + r4] = u;   // 8B aligned
  }
  __syncthreads();
  const int n = tid >> 2, kc = (tid & 3) * 16;
  unsigned short* drow = dst + ((size_t)e * N + n0 + n) * K + k0 + kc;
  const uint4 v0 = *(const uint4*)&LT[n * 72 + kc];      // k = kc..kc+7
  const uint4 v1 = *(const uint4*)&LT[n * 72 + kc + 8];  // k = kc+8..kc+15
  *(uint4*)(drow) = v0;
  *(uint4*)(drow + 8) = v1;
}

// ---------------- grouped GEMM: C = [gelu](A @ Bt[e]^T [+ bias[e]]) ----------------
// A:  [rows][KTOT] bf16 (expert-segmented, 128-padded rows)
// Bt: [E][N][KTOT] bf16 (pre-transposed weights, n-major)
// blockIdx.z selects a K-slice of kbn 64-chunks; z=0 adds bias, z>0 writes C1.
template <int KTOT, int N, bool GELU>
__global__ __launch_bounds__(256, 4)
void moe_gemm(const unsigned short* __restrict__ A,
              const unsigned short* __restrict__ Bt,
              const float* __restrict__ bias,
              unsigned short* __restrict__ C0, unsigned short* __restrict__ C1,
              const int* __restrict__ off, int kbn) {
  __shared__ unsigned short As[128 * 64];
  __shared__ unsigned short Bs[128 * 64];

  const int tiles = off[8] >> 7;
  const int mt = blockIdx.x;
  if (mt >= tiles) return;
  const int row0 = mt << 7;
  int e = 0;
  while (off[e + 1] <= row0) ++e;
  const int n0 = blockIdx.y * 128;
  const int z = blockIdx.z;
  const int kb0 = z * kbn;
  unsigned short* C = z ? C1 : C0;

  const unsigned short* Ap = A + (size_t)row0 * KTOT;
  const unsigned short* Bp = Bt + ((size_t)e * N + n0) * KTOT;
  const float* biasp = bias + (size_t)e * N + n0;

  const int tid = threadIdx.x;
  const int wave = tid >> 6, lane = tid & 63;
  const int qd = lane >> 4, ln = lane & 15;
  const int wm = (wave & 1) << 6, wn = (wave >> 1) << 6;

  f32x4 acc[4][4] = {};

  for (int kb = kb0; kb < kb0 + kbn; ++kb) {
    __syncthreads();
    // stage A and B tiles: 16 KB each, 4 cp16/thread per operand
#pragma unroll
    for (int rr = 0; rr < 4; ++rr) {
      const int p = rr * 256 + tid;          // chunk id 0..1023
      const int r = p >> 3, q = p & 7;
      const int gq = q ^ swz(r);             // swizzled source chunk
      const size_t goff = (size_t)r * KTOT + kb * 64 + gq * 8;
      async_cp16(Ap + goff, As + (size_t)(p & ~63) * 8);
      async_cp16(Bp + goff, Bs + (size_t)(p & ~63) * 8);
    }
    __syncthreads();
    // compute: 2 k-steps x 16 MFMA per wave
#pragma unroll
    for (int s = 0; s < 2; ++s) {
      bf16x8 a[4], b[4];
#pragma unroll
      for (int i = 0; i < 4; ++i) {
        const int m = wm + i * 16 + ln;
        const int pos = (s * 4 + qd) ^ swz(m);
        a[i] = *(const bf16x8*)(As + ((size_t)m * 8 + pos) * 8);
      }
#pragma unroll
      for (int j = 0; j < 4; ++j) {
        const int n = wn + j * 16 + ln;
        const int pos = (s * 4 + qd) ^ swz(n);
        b[j] = *(const bf16x8*)(Bs + ((size_t)n * 8 + pos) * 8);
      }
#pragma unroll
      for (int i = 0; i < 4; ++i)
#pragma unroll
        for (int j = 0; j < 4; ++j)
          acc[i][j] = __builtin_amdgcn_mfma_f32_16x16x32_bf16(a[i], b[j], acc[i][j], 0, 0, 0);
    }
  }

  // epilogue: bias (z==0 only) (+gelu) -> bf16 C
  const bool addb = (z == 0);
#pragma unroll
  for (int j = 0; j < 4; ++j) {
    const int cn = wn + j * 16 + ln;
    const float bv = addb ? biasp[cn] : 0.f;
#pragma unroll
    for (int i = 0; i < 4; ++i) {
#pragma unroll
      for (int r = 0; r < 4; ++r) {
        const int gm = row0 + wm + i * 16 + qd * 4 + r;
        float v = acc[i][j][r] + bv;
        if (GELU) v = 0.5f * v * (1.f + erff(v * 0.70710678118654752f));
        C[(size_t)gm * N + n0 + cn] = f2bf(v);
      }
    }
  }
}

// ---------------- combine: out[t] = p0*y[s0] + p1*y[s1] (y = y0 [+ y1]) ----------------
__global__ __launch_bounds__(256)
void moe_combine(const unsigned short* __restrict__ Ys0,
                 const unsigned short* __restrict__ Ys1,
                 const float* __restrict__ tk_prob,
                 const int* __restrict__ slot_of, float* __restrict__ out,
                 int use2) {
  const int wave = threadIdx.x >> 6, lane = threadIdx.x & 63;
  const int t = blockIdx.x * 4 + wave;
  const float p0 = tk_prob[2 * t], p1 = tk_prob[2 * t + 1];
  const int s0 = slot_of[2 * t], s1 = slot_of[2 * t + 1];
#pragma unroll
  for (int i = 0; i < 4; ++i) {
    const int d = (i * 64 + lane) * 4;
    const ushort4 a = *(const ushort4*)(Ys0 + (size_t)s0 * DDIM + d);
    const ushort4 b = *(const ushort4*)(Ys0 + (size_t)s1 * DDIM + d);
    float4 o;
    o.x = p0 * bf2f(a.x) + p1 * bf2f(b.x);
    o.y = p0 * bf2f(a.y) + p1 * bf2f(b.y);
    o.z = p0 * bf2f(a.z) + p1 * bf2f(b.z);
    o.w = p0 * bf2f(a.w) + p1 * bf2f(b.w);
    if (use2) {
      const ushort4 a2 = *(const ushort4*)(Ys1 + (size_t)s0 * DDIM + d);
      const ushort4 b2 = *(const ushort4*)(Ys1 + (size_t)s1 * DDIM + d);
      o.x += p0 * bf2f(a2.x) + p1 * bf2f(b2.x);
      o.y += p0 * bf2f(a2.y) + p1 * bf2f(b2.y);
      o.z += p0 * bf2f(a2.z) + p1 * bf2f(b2.z);
      o.w += p0 * bf2f(a2.w) + p1 * bf2f(b2.w);
    }
    *(float4*)(out + (size_t)t * DDIM + d) = o;
  }
}

extern "C" void kernel_launch(void* const* d_in, const int* in_sizes, int n_in,
                              void* d_out, int out_size, void* d_ws, size_t ws_size,
                              hipStream_t stream) {
  const float* x  = (const float*)d_in[0];
  const float* rw = (const float*)d_in[1];
  const float* w1 = (const float*)d_in[2];
  const float* b1 = (const float*)d_in[3];
  const float* w2 = (const float*)d_in[4];
  const float* b2 = (const float*)d_in[5];
  float* out = (float*)d_out;

  // workspace layout:
  //   [ctrl 256][tk_idx][tk_prob][slot_of][Xg 18.9M][Hs 75.5M][Bt 67.1M][Ys1 18.9M]
  //   Ys half0 overlays Xg (dead after gemm1); Bt reused for w1 then w2.
  char* w = (char*)d_ws;
  int*   counts   = (int*)(w + 0);        // 8
  int*   off      = (int*)(w + 64);       // 9
  float* meanprob = (float*)(w + 128);    // 8
  int*   tk_idx   = (int*)(w + 256);
  float* tk_prob  = (float*)(w + 33024);
  int*   slot_of  = (int*)(w + 65792);
  unsigned short* Xg  = (unsigned short*)(w + 98816);    // [9216][1024] bf16
  unsigned short* Ys0 = Xg;                              // overlay (post-gemm1)
  unsigned short* Hs  = (unsigned short*)(w + 18973184); // [9216][4096] bf16
  unsigned short* Bt  = (unsigned short*)(w + 94470656); // [8][4096][1024] bf16
  unsigned short* Ys1 = (unsigned short*)(w + 161579520);// [9216][1024] bf16
  const int split = (ws_size >= (size_t)180453888) ? 1 : 0;

  hipMemsetAsync(d_ws, 0, 256, stream);  // counts/off/meanprob
  moe_router<<<dim3(T_TOKENS / 4), dim3(256), 0, stream>>>(x, rw, tk_idx, tk_prob,
                                                           counts, meanprob);
  moe_assign<<<dim3(NEXP), dim3(256), 0, stream>>>(counts, tk_idx, slot_of, off,
                                                   meanprob,
                                                   out + (size_t)T_TOKENS * DDIM);
  moe_scatter<<<dim3(T_TOKENS / 4), dim3(256), 0, stream>>>(x, slot_of, Xg);
  // w1 [E][D][H] -> Bt [E][H][D]
  moe_convw<<<dim3(HDIM / 64, DDIM / 64, NEXP), dim3(256), 0, stream>>>(w1, Bt, DDIM, HDIM);
  moe_gemm<DDIM, HDIM, true><<<dim3(MAXTILES, HDIM / 128, 1), dim3(256), 0, stream>>>(
      Xg, Bt, b1, Hs, Hs, off, DDIM / 64);
  // w2 [E][H][D] -> Bt [E][D][H]
  moe_convw<<<dim3(DDIM / 64, HDIM / 64, NEXP), dim3(256), 0, stream>>>(w2, Bt, HDIM, DDIM);
  if (split) {
    moe_gemm<HDIM, DDIM, false><<<dim3(MAXTILES, DDIM / 128, 2), dim3(256), 0, stream>>>(
        Hs, Bt, b2, Ys0, Ys1, off, HDIM / 128);
  } else {
    moe_gemm<HDIM, DDIM, false><<<dim3(MAXTILES, DDIM / 128, 1), dim3(256), 0, stream>>>(
        Hs, Bt, b2, Ys0, Ys0, off, HDIM / 64);
  }
  moe_combine<<<dim3(T_TOKENS / 4), dim3(256), 0, stream>>>(Ys0, Ys1, tk_prob,
                                                            slot_of, out, split);
}